// Round 6
// baseline (114.599 us; speedup 1.0000x reference)
//
#include <hip/hip_runtime.h>
#include <math.h>
#include <stdint.h>

#define NS 200
#define THASH (1 << 19)
#define TMASK ((1u << 19) - 1u)

__device__ __forceinline__ float sigmoidf_(float v) {
    return 1.0f / (1.0f + __expf(-v));
}

// Kernel 1: one block (256 threads) per ray; lane s = sample s.
// Run-leader dedup + even-x float2 corner pairing (hash delta along x is 1
// when x0 is even, so the two x-corners of each (y,z) pair share an aligned
// 8B slot -> 4 requests instead of 8).
__global__ __launch_bounds__(256) void k_label(
        const float* __restrict__ x,
        const float* __restrict__ tlab,
        const float* __restrict__ wlab, const float* __restrict__ blab,
        float* __restrict__ hits, float* __restrict__ labels,
        int* __restrict__ firsts)
{
    const uint32_t P2 = 2654435761u, P3 = 805459861u;
    const int b = blockIdx.x;
    const int tid = threadIdx.x;
    const int lane = tid & 63;
    const int wid = tid >> 6;
    const float4 ray = *(const float4*)(x + 4 * (size_t)b);

    const int s_eff = tid < NS ? tid : NS - 1;
    const float t = (float)s_eff * (1.0f / 199.0f);
    const float px = ray.x * (1.0f - t) + ray.z * t;
    const float py = ray.y * (1.0f - t) + ray.w * t;
    const float pz = t;

    // finest level (res = 128); coarser levels derived by shifts
    const float xf4 = px * 128.0f, yf4 = py * 128.0f, zf4 = pz * 128.0f;
    const float fx4 = floorf(xf4), fy4 = floorf(yf4), fz4 = floorf(zf4);
    const uint32_t x4 = (uint32_t)(int)fx4;
    const uint32_t y4 = (uint32_t)(int)fy4;
    const uint32_t z4 = (uint32_t)(int)fz4;
    const uint32_t cell4 = x4 | (y4 << 10) | (z4 << 20);
    const uint32_t prev = __shfl_up(cell4, 1);
    const uint32_t diff = cell4 ^ prev;   // garbage at lane 0 (forced leader)

    float acc = blab[0];

    // ---- levels 0..3 with run-dedup ----
    #pragma unroll
    for (int l = 0; l < 4; ++l) {
        const int k = 4 - l;
        const uint32_t fm = 0x3FFu & ~((1u << k) - 1u);
        const uint32_t m_l = fm | (fm << 10) | (fm << 20);
        const bool leader = (lane == 0) || ((diff & m_l) != 0u);
        const uint64_t bal = __ballot(leader);
        const uint64_t below = bal & (~0ull >> (63 - lane));
        const int ldr = 63 - __clzll(below);

        const uint32_t x0 = x4 >> k, y0 = y4 >> k, z0 = z4 >> k;
        const float sc = 1.0f / (float)(1 << k);     // exact 2^-k
        const float wx = fmaf(xf4, sc, -(float)x0);
        const float wy = fmaf(yf4, sc, -(float)y0);
        const float wz = fmaf(zf4, sc, -(float)z0);

        float v0 = 0.f, v1 = 0.f, v2 = 0.f, v3 = 0.f,
              v4v = 0.f, v5 = 0.f, v6 = 0.f, v7 = 0.f;
        if (leader) {
            const uint32_t hy0 = y0 * P2, hz0 = z0 * P3;
            const uint32_t dy = hy0 ^ (hy0 + P2);
            const uint32_t dz = hz0 ^ (hz0 + P3);
            const float* __restrict__ tl = tlab + (size_t)l * THASH;
            const uint32_t base = x0 ^ hy0 ^ hz0;
            if (x0 & 1u) {
                // odd x0: hash delta along x is wide -> 8 scalar loads
                const uint32_t dx = x0 ^ (x0 + 1u);
                v0  = tl[ base                 & TMASK];
                v1  = tl[(base ^ dz)           & TMASK];
                v2  = tl[(base ^ dy)           & TMASK];
                v3  = tl[(base ^ dy ^ dz)      & TMASK];
                v4v = tl[(base ^ dx)           & TMASK];
                v5  = tl[(base ^ dx ^ dz)      & TMASK];
                v6  = tl[(base ^ dx ^ dy)      & TMASK];
                v7  = tl[(base ^ dx ^ dy ^ dz) & TMASK];
            } else {
                // even x0: dx == 1 -> each (y,z) corner pair is {i, i^1}
                const uint32_t i00 =  base             & TMASK;
                const uint32_t i01 = (base ^ dz)       & TMASK;
                const uint32_t i10 = (base ^ dy)       & TMASK;
                const uint32_t i11 = (base ^ dy ^ dz)  & TMASK;
                const float2 p00 = *(const float2*)(tl + (i00 & ~1u));
                const float2 p01 = *(const float2*)(tl + (i01 & ~1u));
                const float2 p10 = *(const float2*)(tl + (i10 & ~1u));
                const float2 p11 = *(const float2*)(tl + (i11 & ~1u));
                const bool l00 = (i00 & 1u) == 0u;
                const bool l01 = (i01 & 1u) == 0u;
                const bool l10 = (i10 & 1u) == 0u;
                const bool l11 = (i11 & 1u) == 0u;
                v0  = l00 ? p00.x : p00.y;  v4v = l00 ? p00.y : p00.x;
                v1  = l01 ? p01.x : p01.y;  v5  = l01 ? p01.y : p01.x;
                v2  = l10 ? p10.x : p10.y;  v6  = l10 ? p10.y : p10.x;
                v3  = l11 ? p11.x : p11.y;  v7  = l11 ? p11.y : p11.x;
            }
        }
        v0  = __shfl(v0, ldr);  v1 = __shfl(v1, ldr);
        v2  = __shfl(v2, ldr);  v3 = __shfl(v3, ldr);
        v4v = __shfl(v4v, ldr); v5 = __shfl(v5, ldr);
        v6  = __shfl(v6, ldr);  v7 = __shfl(v7, ldr);

        const float c00 = fmaf(wz, v1 - v0, v0);
        const float c01 = fmaf(wz, v3 - v2, v2);
        const float c10 = fmaf(wz, v5 - v4v, v4v);
        const float c11 = fmaf(wz, v7 - v6, v6);
        const float c0 = fmaf(wy, c01 - c00, c00);
        const float c1 = fmaf(wy, c11 - c10, c10);
        const float cv = fmaf(wx, c1 - c0, c0);
        acc = fmaf(cv, wlab[l], acc);
    }

    // ---- level 4 (res=128): runs ~1 sample, fetch directly (with pairing) ----
    {
        const float wx = xf4 - fx4, wy = yf4 - fy4, wz = zf4 - fz4;
        const uint32_t hy0 = y4 * P2, hz0 = z4 * P3;
        const uint32_t base = x4 ^ hy0 ^ hz0;
        const uint32_t dy = hy0 ^ (hy0 + P2);
        const uint32_t dz = hz0 ^ (hz0 + P3);
        const float* __restrict__ tl = tlab + (size_t)4 * THASH;
        float v0, v1, v2, v3, v4v, v5, v6, v7;
        if (x4 & 1u) {
            const uint32_t dx = x4 ^ (x4 + 1u);
            v0  = tl[ base                 & TMASK];
            v1  = tl[(base ^ dz)           & TMASK];
            v2  = tl[(base ^ dy)           & TMASK];
            v3  = tl[(base ^ dy ^ dz)      & TMASK];
            v4v = tl[(base ^ dx)           & TMASK];
            v5  = tl[(base ^ dx ^ dz)      & TMASK];
            v6  = tl[(base ^ dx ^ dy)      & TMASK];
            v7  = tl[(base ^ dx ^ dy ^ dz) & TMASK];
        } else {
            const uint32_t i00 =  base             & TMASK;
            const uint32_t i01 = (base ^ dz)       & TMASK;
            const uint32_t i10 = (base ^ dy)       & TMASK;
            const uint32_t i11 = (base ^ dy ^ dz)  & TMASK;
            const float2 p00 = *(const float2*)(tl + (i00 & ~1u));
            const float2 p01 = *(const float2*)(tl + (i01 & ~1u));
            const float2 p10 = *(const float2*)(tl + (i10 & ~1u));
            const float2 p11 = *(const float2*)(tl + (i11 & ~1u));
            const bool l00 = (i00 & 1u) == 0u;
            const bool l01 = (i01 & 1u) == 0u;
            const bool l10 = (i10 & 1u) == 0u;
            const bool l11 = (i11 & 1u) == 0u;
            v0  = l00 ? p00.x : p00.y;  v4v = l00 ? p00.y : p00.x;
            v1  = l01 ? p01.x : p01.y;  v5  = l01 ? p01.y : p01.x;
            v2  = l10 ? p10.x : p10.y;  v6  = l10 ? p10.y : p10.x;
            v3  = l11 ? p11.x : p11.y;  v7  = l11 ? p11.y : p11.x;
        }
        const float c00 = fmaf(wz, v1 - v0, v0);
        const float c01 = fmaf(wz, v3 - v2, v2);
        const float c10 = fmaf(wz, v5 - v4v, v4v);
        const float c11 = fmaf(wz, v7 - v6, v6);
        const float c0 = fmaf(wy, c01 - c00, c00);
        const float c1 = fmaf(wy, c11 - c10, c10);
        const float cv = fmaf(wx, c1 - c0, c0);
        acc = fmaf(cv, wlab[4], acc);
    }

    float lab = -1.0f;
    int cand = NS;
    if (tid < NS) {
        lab = sigmoidf_(acc);
        labels[(size_t)b * NS + tid] = lab;
        if (lab > 0.5f) cand = tid;
    }

    // ---- block reduce: max(label), min(first idx > 0.5) ----
    __shared__ float wmax[4];
    __shared__ int wmin[4];
    float m = lab;
    int c = cand;
    #pragma unroll
    for (int off = 32; off > 0; off >>= 1) {
        m = fmaxf(m, __shfl_xor(m, off));
        c = min(c, __shfl_xor(c, off));
    }
    if (lane == 0) { wmax[wid] = m; wmin[wid] = c; }
    __syncthreads();
    if (tid == 0) {
        float mm = fmaxf(fmaxf(wmax[0], wmax[1]), fmaxf(wmax[2], wmax[3]));
        int cc = min(min(wmin[0], wmin[1]), min(wmin[2], wmin[3]));
        hits[b] = mm;
        firsts[b] = (cc >= NS) ? 0 : cc;
    }
}

// Kernel 2: 1024 blocks x 16 rays. Phase A: 15 iters of one gather/thread
// -> feat[16][120] in LDS. Phase B: each wave runs the MLP for 4 rays.
#define RPB 16
__global__ __launch_bounds__(256) void k_rgb(
        const float* __restrict__ x,
        const float* __restrict__ trgb,
        const int* __restrict__ firsts,
        const float* __restrict__ W1, const float* __restrict__ b1,
        const float* __restrict__ W2, const float* __restrict__ b2,
        const float* __restrict__ W3, const float* __restrict__ b3,
        const float* __restrict__ W4, const float* __restrict__ b4,
        float* __restrict__ rgb)
{
    const uint32_t P2 = 2654435761u, P3 = 805459861u;
    const int tid = threadIdx.x;
    const int lane = tid & 63;
    const int wid = tid >> 6;
    const int rayBase = blockIdx.x * RPB;

    __shared__ float feat[RPB][120];
    __shared__ float hs[RPB][64];

    // ---- Phase A: feature gather ----
    const int corner = tid & 7;
    const int rp = tid >> 3;
    const int ray = rp >> 1;
    const int pairHalf = rp & 1;
    const int bi = (corner >> 2) & 1, bj = (corner >> 1) & 1, bk = corner & 1;

    const float4 rd = *(const float4*)(x + 4 * (size_t)(rayBase + ray));
    const int first = firsts[rayBase + ray];

    #pragma unroll
    for (int it = 0; it < 15; ++it) {
        const int pair = pairHalf * 15 + it;   // 0..29
        const int si = pair / 6;
        const int l = pair % 6;
        int scl = first + si - 2;
        scl = scl < 0 ? 0 : (scl > NS - 1 ? NS - 1 : scl);
        const float t = (float)scl * (1.0f / 199.0f);
        const float px = rd.x * (1.0f - t) + rd.z * t;
        const float py = rd.y * (1.0f - t) + rd.w * t;
        const float pz = t;
        const int res = 4 << l;
        const float xf = px * (float)res, yf = py * (float)res, zf = pz * (float)res;
        const float fx = floorf(xf), fy = floorf(yf), fz = floorf(zf);
        const float wx = xf - fx, wy = yf - fy, wz = zf - fz;
        const uint32_t x0 = (uint32_t)(int)fx, y0 = (uint32_t)(int)fy, z0 = (uint32_t)(int)fz;
        const uint32_t hx = x0 + (uint32_t)bi;
        const uint32_t hy = (y0 + (uint32_t)bj) * P2;
        const uint32_t hz = (z0 + (uint32_t)bk) * P3;
        const uint32_t idx = (hx ^ hy ^ hz) & TMASK;
        const float cw = (bi ? wx : 1.0f - wx) * (bj ? wy : 1.0f - wy) * (bk ? wz : 1.0f - wz);
        const float4 tv = *(const float4*)(trgb + (((size_t)l << 19) + idx) * 4);
        float vx = tv.x * cw, vy = tv.y * cw, vz = tv.z * cw, vw = tv.w * cw;
        #pragma unroll
        for (int mm = 1; mm < 8; mm <<= 1) {
            vx += __shfl_xor(vx, mm);
            vy += __shfl_xor(vy, mm);
            vz += __shfl_xor(vz, mm);
            vw += __shfl_xor(vw, mm);
        }
        if (corner == 0) {
            float* f = &feat[ray][si * 24 + l * 4];
            f[0] = vx; f[1] = vy; f[2] = vz; f[3] = vw;
        }
    }
    __syncthreads();

    // ---- Phase B: MLP, 4 rays per wave ----
    const int r0 = wid * 4;

    float a0 = b1[lane], a1 = a0, a2 = a0, a3 = a0;
    #pragma unroll 6
    for (int i = 0; i < 120; i += 4) {
        const float4 f0 = *(const float4*)(&feat[r0 + 0][i]);
        const float4 f1 = *(const float4*)(&feat[r0 + 1][i]);
        const float4 f2 = *(const float4*)(&feat[r0 + 2][i]);
        const float4 f3 = *(const float4*)(&feat[r0 + 3][i]);
        #pragma unroll
        for (int j = 0; j < 4; ++j) {
            const float wv = W1[(i + j) * 64 + lane];
            a0 = fmaf(((const float*)&f0)[j], wv, a0);
            a1 = fmaf(((const float*)&f1)[j], wv, a1);
            a2 = fmaf(((const float*)&f2)[j], wv, a2);
            a3 = fmaf(((const float*)&f3)[j], wv, a3);
        }
    }
    hs[r0 + 0][lane] = fmaxf(a0, 0.f);
    hs[r0 + 1][lane] = fmaxf(a1, 0.f);
    hs[r0 + 2][lane] = fmaxf(a2, 0.f);
    hs[r0 + 3][lane] = fmaxf(a3, 0.f);
    __syncthreads();

    a0 = b2[lane]; a1 = a0; a2 = a0; a3 = a0;
    #pragma unroll 4
    for (int i = 0; i < 64; i += 4) {
        const float4 f0 = *(const float4*)(&hs[r0 + 0][i]);
        const float4 f1 = *(const float4*)(&hs[r0 + 1][i]);
        const float4 f2 = *(const float4*)(&hs[r0 + 2][i]);
        const float4 f3 = *(const float4*)(&hs[r0 + 3][i]);
        #pragma unroll
        for (int j = 0; j < 4; ++j) {
            const float wv = W2[(i + j) * 64 + lane];
            a0 = fmaf(((const float*)&f0)[j], wv, a0);
            a1 = fmaf(((const float*)&f1)[j], wv, a1);
            a2 = fmaf(((const float*)&f2)[j], wv, a2);
            a3 = fmaf(((const float*)&f3)[j], wv, a3);
        }
    }
    __syncthreads();
    hs[r0 + 0][lane] = fmaxf(a0, 0.f);
    hs[r0 + 1][lane] = fmaxf(a1, 0.f);
    hs[r0 + 2][lane] = fmaxf(a2, 0.f);
    hs[r0 + 3][lane] = fmaxf(a3, 0.f);
    __syncthreads();

    a0 = b3[lane]; a1 = a0; a2 = a0; a3 = a0;
    #pragma unroll 4
    for (int i = 0; i < 64; i += 4) {
        const float4 f0 = *(const float4*)(&hs[r0 + 0][i]);
        const float4 f1 = *(const float4*)(&hs[r0 + 1][i]);
        const float4 f2 = *(const float4*)(&hs[r0 + 2][i]);
        const float4 f3 = *(const float4*)(&hs[r0 + 3][i]);
        #pragma unroll
        for (int j = 0; j < 4; ++j) {
            const float wv = W3[(i + j) * 64 + lane];
            a0 = fmaf(((const float*)&f0)[j], wv, a0);
            a1 = fmaf(((const float*)&f1)[j], wv, a1);
            a2 = fmaf(((const float*)&f2)[j], wv, a2);
            a3 = fmaf(((const float*)&f3)[j], wv, a3);
        }
    }
    __syncthreads();
    hs[r0 + 0][lane] = fmaxf(a0, 0.f);
    hs[r0 + 1][lane] = fmaxf(a1, 0.f);
    hs[r0 + 2][lane] = fmaxf(a2, 0.f);
    hs[r0 + 3][lane] = fmaxf(a3, 0.f);
    __syncthreads();

    if (lane < 12) {
        const int r = lane / 3, ch = lane % 3;
        float acc = b4[ch];
        #pragma unroll 8
        for (int j = 0; j < 64; ++j)
            acc = fmaf(hs[r0 + r][j], W4[j * 3 + ch], acc);
        rgb[(size_t)(rayBase + r0 + r) * 3 + ch] = acc;
    }
}

extern "C" void kernel_launch(void* const* d_in, const int* in_sizes, int n_in,
                              void* d_out, int out_size, void* d_ws, size_t ws_size,
                              hipStream_t stream) {
    const float* x    = (const float*)d_in[0];
    const float* tlab = (const float*)d_in[1];
    const float* trgb = (const float*)d_in[2];
    const float* wlab = (const float*)d_in[3];
    const float* blab = (const float*)d_in[4];
    const float* W1   = (const float*)d_in[5];
    const float* b1   = (const float*)d_in[6];
    const float* W2   = (const float*)d_in[7];
    const float* b2   = (const float*)d_in[8];
    const float* W3   = (const float*)d_in[9];
    const float* b3   = (const float*)d_in[10];
    const float* W4   = (const float*)d_in[11];
    const float* b4   = (const float*)d_in[12];

    const int B = in_sizes[0] / 4;  // 16384

    float* hits   = (float*)d_out;                       // [B]
    float* labels = hits + B;                            // [B*NS]
    float* rgbout = labels + (size_t)B * NS;             // [B*3]
    int* firsts   = (int*)d_ws;                          // [B]

    k_label<<<B, 256, 0, stream>>>(x, tlab, wlab, blab, hits, labels, firsts);
    k_rgb<<<B / RPB, 256, 0, stream>>>(x, trgb, firsts,
                                       W1, b1, W2, b2, W3, b3, W4, b4, rgbout);
}

// Round 7
// 106.257 us; speedup vs baseline: 1.0785x; 1.0785x over previous
//
#include <hip/hip_runtime.h>
#include <math.h>
#include <stdint.h>

#define NS 200
#define THASH (1 << 19)
#define TMASK ((1u << 19) - 1u)

__device__ __forceinline__ float sigmoidf_(float v) {
    return 1.0f / (1.0f + __expf(-v));
}

// Kernel 1: one block (256 threads) per ray; lane s = sample s.
// Run-leader dedup (packed shfl_up at finest res; coarser = shifts).
// Software-pipelined: ALL 40 gathers (4 leader-masked levels + level 4
// unconditional) are issued before any shfl/interp consumption -> one
// latency exposure instead of five serial round-trips.
__global__ __launch_bounds__(256) void k_label(
        const float* __restrict__ x,
        const float* __restrict__ tlab,
        const float* __restrict__ wlab, const float* __restrict__ blab,
        float* __restrict__ hits, float* __restrict__ labels,
        int* __restrict__ firsts)
{
    const uint32_t P2 = 2654435761u, P3 = 805459861u;
    const int b = blockIdx.x;
    const int tid = threadIdx.x;
    const int lane = tid & 63;
    const int wid = tid >> 6;
    const float4 ray = *(const float4*)(x + 4 * (size_t)b);

    const int s_eff = tid < NS ? tid : NS - 1;
    const float t = (float)s_eff * (1.0f / 199.0f);
    const float px = ray.x * (1.0f - t) + ray.z * t;
    const float py = ray.y * (1.0f - t) + ray.w * t;
    const float pz = t;

    // finest level (res = 128); coarser levels derived by shifts
    const float xf4 = px * 128.0f, yf4 = py * 128.0f, zf4 = pz * 128.0f;
    const float fx4 = floorf(xf4), fy4 = floorf(yf4), fz4 = floorf(zf4);
    const uint32_t x4 = (uint32_t)(int)fx4;
    const uint32_t y4 = (uint32_t)(int)fy4;
    const uint32_t z4 = (uint32_t)(int)fz4;
    const uint32_t cell4 = x4 | (y4 << 10) | (z4 << 20);
    const uint32_t prev = __shfl_up(cell4, 1);
    const uint32_t diff = cell4 ^ prev;   // garbage at lane 0 (forced leader)

    float v[5][8];        // loaded corner values (constant-indexed after unroll)
    int ldrs[4];

    // ---- Phase A: leader calc + ISSUE all loads, levels 0..3 masked ----
    #pragma unroll
    for (int l = 0; l < 4; ++l) {
        const int k = 4 - l;
        const uint32_t fm = 0x3FFu & ~((1u << k) - 1u);
        const uint32_t m_l = fm | (fm << 10) | (fm << 20);
        const bool leader = (lane == 0) || ((diff & m_l) != 0u);
        const uint64_t bal = __ballot(leader);
        const uint64_t below = bal & (~0ull >> (63 - lane));
        ldrs[l] = 63 - __clzll(below);

        if (leader) {
            const uint32_t x0 = x4 >> k, y0 = y4 >> k, z0 = z4 >> k;
            const uint32_t hy0 = y0 * P2, hz0 = z0 * P3;
            const uint32_t base = x0 ^ hy0 ^ hz0;
            const uint32_t dx = x0 ^ (x0 + 1u);
            const uint32_t dy = hy0 ^ (hy0 + P2);
            const uint32_t dz = hz0 ^ (hz0 + P3);
            const float* __restrict__ tl = tlab + (size_t)l * THASH;
            v[l][0] = tl[ base                 & TMASK];
            v[l][1] = tl[(base ^ dz)           & TMASK];
            v[l][2] = tl[(base ^ dy)           & TMASK];
            v[l][3] = tl[(base ^ dy ^ dz)      & TMASK];
            v[l][4] = tl[(base ^ dx)           & TMASK];
            v[l][5] = tl[(base ^ dx ^ dz)      & TMASK];
            v[l][6] = tl[(base ^ dx ^ dy)      & TMASK];
            v[l][7] = tl[(base ^ dx ^ dy ^ dz) & TMASK];
        }
    }
    // level 4 (res=128): runs ~1 sample, every lane fetches its own corners
    {
        const uint32_t hy0 = y4 * P2, hz0 = z4 * P3;
        const uint32_t base = x4 ^ hy0 ^ hz0;
        const uint32_t dx = x4 ^ (x4 + 1u);
        const uint32_t dy = hy0 ^ (hy0 + P2);
        const uint32_t dz = hz0 ^ (hz0 + P3);
        const float* __restrict__ tl = tlab + (size_t)4 * THASH;
        v[4][0] = tl[ base                 & TMASK];
        v[4][1] = tl[(base ^ dz)           & TMASK];
        v[4][2] = tl[(base ^ dy)           & TMASK];
        v[4][3] = tl[(base ^ dy ^ dz)      & TMASK];
        v[4][4] = tl[(base ^ dx)           & TMASK];
        v[4][5] = tl[(base ^ dx ^ dz)      & TMASK];
        v[4][6] = tl[(base ^ dx ^ dy)      & TMASK];
        v[4][7] = tl[(base ^ dx ^ dy ^ dz) & TMASK];
    }

    // ---- Phase B: consume (shfl broadcast + trilinear interp) ----
    float acc = blab[0];
    #pragma unroll
    for (int l = 0; l < 4; ++l) {
        const int k = 4 - l;
        const uint32_t x0 = x4 >> k, y0 = y4 >> k, z0 = z4 >> k;
        const float sc = 1.0f / (float)(1 << k);     // exact 2^-k
        const float wx = fmaf(xf4, sc, -(float)x0);
        const float wy = fmaf(yf4, sc, -(float)y0);
        const float wz = fmaf(zf4, sc, -(float)z0);

        const int ldr = ldrs[l];
        const float v0 = __shfl(v[l][0], ldr);
        const float v1 = __shfl(v[l][1], ldr);
        const float v2 = __shfl(v[l][2], ldr);
        const float v3 = __shfl(v[l][3], ldr);
        const float v4v = __shfl(v[l][4], ldr);
        const float v5 = __shfl(v[l][5], ldr);
        const float v6 = __shfl(v[l][6], ldr);
        const float v7 = __shfl(v[l][7], ldr);

        const float c00 = fmaf(wz, v1 - v0, v0);
        const float c01 = fmaf(wz, v3 - v2, v2);
        const float c10 = fmaf(wz, v5 - v4v, v4v);
        const float c11 = fmaf(wz, v7 - v6, v6);
        const float c0 = fmaf(wy, c01 - c00, c00);
        const float c1 = fmaf(wy, c11 - c10, c10);
        const float cv = fmaf(wx, c1 - c0, c0);
        acc = fmaf(cv, wlab[l], acc);
    }
    {
        const float wx = xf4 - fx4, wy = yf4 - fy4, wz = zf4 - fz4;
        const float c00 = fmaf(wz, v[4][1] - v[4][0], v[4][0]);
        const float c01 = fmaf(wz, v[4][3] - v[4][2], v[4][2]);
        const float c10 = fmaf(wz, v[4][5] - v[4][4], v[4][4]);
        const float c11 = fmaf(wz, v[4][7] - v[4][6], v[4][6]);
        const float c0 = fmaf(wy, c01 - c00, c00);
        const float c1 = fmaf(wy, c11 - c10, c10);
        const float cv = fmaf(wx, c1 - c0, c0);
        acc = fmaf(cv, wlab[4], acc);
    }

    float lab = -1.0f;
    int cand = NS;
    if (tid < NS) {
        lab = sigmoidf_(acc);
        labels[(size_t)b * NS + tid] = lab;
        if (lab > 0.5f) cand = tid;
    }

    // ---- block reduce: max(label), min(first idx > 0.5) ----
    __shared__ float wmax[4];
    __shared__ int wmin[4];
    float m = lab;
    int c = cand;
    #pragma unroll
    for (int off = 32; off > 0; off >>= 1) {
        m = fmaxf(m, __shfl_xor(m, off));
        c = min(c, __shfl_xor(c, off));
    }
    if (lane == 0) { wmax[wid] = m; wmin[wid] = c; }
    __syncthreads();
    if (tid == 0) {
        float mm = fmaxf(fmaxf(wmax[0], wmax[1]), fmaxf(wmax[2], wmax[3]));
        int cc = min(min(wmin[0], wmin[1]), min(wmin[2], wmin[3]));
        hits[b] = mm;
        firsts[b] = (cc >= NS) ? 0 : cc;
    }
}

// Kernel 2: 1024 blocks x 16 rays. Phase A: 15 iters of one gather/thread
// -> feat[16][120] in LDS. Phase B: each wave runs the MLP for 4 rays.
#define RPB 16
__global__ __launch_bounds__(256) void k_rgb(
        const float* __restrict__ x,
        const float* __restrict__ trgb,
        const int* __restrict__ firsts,
        const float* __restrict__ W1, const float* __restrict__ b1,
        const float* __restrict__ W2, const float* __restrict__ b2,
        const float* __restrict__ W3, const float* __restrict__ b3,
        const float* __restrict__ W4, const float* __restrict__ b4,
        float* __restrict__ rgb)
{
    const uint32_t P2 = 2654435761u, P3 = 805459861u;
    const int tid = threadIdx.x;
    const int lane = tid & 63;
    const int wid = tid >> 6;
    const int rayBase = blockIdx.x * RPB;

    __shared__ float feat[RPB][120];
    __shared__ float hs[RPB][64];

    // ---- Phase A: feature gather ----
    const int corner = tid & 7;
    const int rp = tid >> 3;
    const int ray = rp >> 1;
    const int pairHalf = rp & 1;
    const int bi = (corner >> 2) & 1, bj = (corner >> 1) & 1, bk = corner & 1;

    const float4 rd = *(const float4*)(x + 4 * (size_t)(rayBase + ray));
    const int first = firsts[rayBase + ray];

    #pragma unroll
    for (int it = 0; it < 15; ++it) {
        const int pair = pairHalf * 15 + it;   // 0..29
        const int si = pair / 6;
        const int l = pair % 6;
        int scl = first + si - 2;
        scl = scl < 0 ? 0 : (scl > NS - 1 ? NS - 1 : scl);
        const float t = (float)scl * (1.0f / 199.0f);
        const float px = rd.x * (1.0f - t) + rd.z * t;
        const float py = rd.y * (1.0f - t) + rd.w * t;
        const float pz = t;
        const int res = 4 << l;
        const float xf = px * (float)res, yf = py * (float)res, zf = pz * (float)res;
        const float fx = floorf(xf), fy = floorf(yf), fz = floorf(zf);
        const float wx = xf - fx, wy = yf - fy, wz = zf - fz;
        const uint32_t x0 = (uint32_t)(int)fx, y0 = (uint32_t)(int)fy, z0 = (uint32_t)(int)fz;
        const uint32_t hx = x0 + (uint32_t)bi;
        const uint32_t hy = (y0 + (uint32_t)bj) * P2;
        const uint32_t hz = (z0 + (uint32_t)bk) * P3;
        const uint32_t idx = (hx ^ hy ^ hz) & TMASK;
        const float cw = (bi ? wx : 1.0f - wx) * (bj ? wy : 1.0f - wy) * (bk ? wz : 1.0f - wz);
        const float4 tv = *(const float4*)(trgb + (((size_t)l << 19) + idx) * 4);
        float vx = tv.x * cw, vy = tv.y * cw, vz = tv.z * cw, vw = tv.w * cw;
        #pragma unroll
        for (int mm = 1; mm < 8; mm <<= 1) {
            vx += __shfl_xor(vx, mm);
            vy += __shfl_xor(vy, mm);
            vz += __shfl_xor(vz, mm);
            vw += __shfl_xor(vw, mm);
        }
        if (corner == 0) {
            float* f = &feat[ray][si * 24 + l * 4];
            f[0] = vx; f[1] = vy; f[2] = vz; f[3] = vw;
        }
    }
    __syncthreads();

    // ---- Phase B: MLP, 4 rays per wave ----
    const int r0 = wid * 4;

    float a0 = b1[lane], a1 = a0, a2 = a0, a3 = a0;
    #pragma unroll 6
    for (int i = 0; i < 120; i += 4) {
        const float4 f0 = *(const float4*)(&feat[r0 + 0][i]);
        const float4 f1 = *(const float4*)(&feat[r0 + 1][i]);
        const float4 f2 = *(const float4*)(&feat[r0 + 2][i]);
        const float4 f3 = *(const float4*)(&feat[r0 + 3][i]);
        #pragma unroll
        for (int j = 0; j < 4; ++j) {
            const float wv = W1[(i + j) * 64 + lane];
            a0 = fmaf(((const float*)&f0)[j], wv, a0);
            a1 = fmaf(((const float*)&f1)[j], wv, a1);
            a2 = fmaf(((const float*)&f2)[j], wv, a2);
            a3 = fmaf(((const float*)&f3)[j], wv, a3);
        }
    }
    hs[r0 + 0][lane] = fmaxf(a0, 0.f);
    hs[r0 + 1][lane] = fmaxf(a1, 0.f);
    hs[r0 + 2][lane] = fmaxf(a2, 0.f);
    hs[r0 + 3][lane] = fmaxf(a3, 0.f);
    __syncthreads();

    a0 = b2[lane]; a1 = a0; a2 = a0; a3 = a0;
    #pragma unroll 4
    for (int i = 0; i < 64; i += 4) {
        const float4 f0 = *(const float4*)(&hs[r0 + 0][i]);
        const float4 f1 = *(const float4*)(&hs[r0 + 1][i]);
        const float4 f2 = *(const float4*)(&hs[r0 + 2][i]);
        const float4 f3 = *(const float4*)(&hs[r0 + 3][i]);
        #pragma unroll
        for (int j = 0; j < 4; ++j) {
            const float wv = W2[(i + j) * 64 + lane];
            a0 = fmaf(((const float*)&f0)[j], wv, a0);
            a1 = fmaf(((const float*)&f1)[j], wv, a1);
            a2 = fmaf(((const float*)&f2)[j], wv, a2);
            a3 = fmaf(((const float*)&f3)[j], wv, a3);
        }
    }
    __syncthreads();
    hs[r0 + 0][lane] = fmaxf(a0, 0.f);
    hs[r0 + 1][lane] = fmaxf(a1, 0.f);
    hs[r0 + 2][lane] = fmaxf(a2, 0.f);
    hs[r0 + 3][lane] = fmaxf(a3, 0.f);
    __syncthreads();

    a0 = b3[lane]; a1 = a0; a2 = a0; a3 = a0;
    #pragma unroll 4
    for (int i = 0; i < 64; i += 4) {
        const float4 f0 = *(const float4*)(&hs[r0 + 0][i]);
        const float4 f1 = *(const float4*)(&hs[r0 + 1][i]);
        const float4 f2 = *(const float4*)(&hs[r0 + 2][i]);
        const float4 f3 = *(const float4*)(&hs[r0 + 3][i]);
        #pragma unroll
        for (int j = 0; j < 4; ++j) {
            const float wv = W3[(i + j) * 64 + lane];
            a0 = fmaf(((const float*)&f0)[j], wv, a0);
            a1 = fmaf(((const float*)&f1)[j], wv, a1);
            a2 = fmaf(((const float*)&f2)[j], wv, a2);
            a3 = fmaf(((const float*)&f3)[j], wv, a3);
        }
    }
    __syncthreads();
    hs[r0 + 0][lane] = fmaxf(a0, 0.f);
    hs[r0 + 1][lane] = fmaxf(a1, 0.f);
    hs[r0 + 2][lane] = fmaxf(a2, 0.f);
    hs[r0 + 3][lane] = fmaxf(a3, 0.f);
    __syncthreads();

    if (lane < 12) {
        const int r = lane / 3, ch = lane % 3;
        float acc = b4[ch];
        #pragma unroll 8
        for (int j = 0; j < 64; ++j)
            acc = fmaf(hs[r0 + r][j], W4[j * 3 + ch], acc);
        rgb[(size_t)(rayBase + r0 + r) * 3 + ch] = acc;
    }
}

extern "C" void kernel_launch(void* const* d_in, const int* in_sizes, int n_in,
                              void* d_out, int out_size, void* d_ws, size_t ws_size,
                              hipStream_t stream) {
    const float* x    = (const float*)d_in[0];
    const float* tlab = (const float*)d_in[1];
    const float* trgb = (const float*)d_in[2];
    const float* wlab = (const float*)d_in[3];
    const float* blab = (const float*)d_in[4];
    const float* W1   = (const float*)d_in[5];
    const float* b1   = (const float*)d_in[6];
    const float* W2   = (const float*)d_in[7];
    const float* b2   = (const float*)d_in[8];
    const float* W3   = (const float*)d_in[9];
    const float* b3   = (const float*)d_in[10];
    const float* W4   = (const float*)d_in[11];
    const float* b4   = (const float*)d_in[12];

    const int B = in_sizes[0] / 4;  // 16384

    float* hits   = (float*)d_out;                       // [B]
    float* labels = hits + B;                            // [B*NS]
    float* rgbout = labels + (size_t)B * NS;             // [B*3]
    int* firsts   = (int*)d_ws;                          // [B]

    k_label<<<B, 256, 0, stream>>>(x, tlab, wlab, blab, hits, labels, firsts);
    k_rgb<<<B / RPB, 256, 0, stream>>>(x, trgb, firsts,
                                       W1, b1, W2, b2, W3, b3, W4, b4, rgbout);
}

// Round 8
// 105.663 us; speedup vs baseline: 1.0846x; 1.0056x over previous
//
#include <hip/hip_runtime.h>
#include <math.h>
#include <stdint.h>

#define NS 200
#define THASH (1 << 19)
#define TMASK ((1u << 19) - 1u)

__device__ __forceinline__ float sigmoidf_(float v) {
    return 1.0f / (1.0f + __expf(-v));
}

#define DECL8(P) float P##0=0.f,P##1=0.f,P##2=0.f,P##3=0.f,P##4=0.f,P##5=0.f,P##6=0.f,P##7=0.f;

#define LOAD8(P, TL, BASE, DX, DY, DZ) \
    P##0 = (TL)[ (BASE)                       & TMASK]; \
    P##1 = (TL)[((BASE) ^ (DZ))               & TMASK]; \
    P##2 = (TL)[((BASE) ^ (DY))               & TMASK]; \
    P##3 = (TL)[((BASE) ^ (DY) ^ (DZ))        & TMASK]; \
    P##4 = (TL)[((BASE) ^ (DX))               & TMASK]; \
    P##5 = (TL)[((BASE) ^ (DX) ^ (DZ))        & TMASK]; \
    P##6 = (TL)[((BASE) ^ (DX) ^ (DY))        & TMASK]; \
    P##7 = (TL)[((BASE) ^ (DX) ^ (DY) ^ (DZ)) & TMASK];

// trilinear lerp of q0..q7 with weights wx,wy,wz -> cv
#define LERP8(Q, WX, WY, WZ, CV) \
    { const float c00 = fmaf((WZ), Q##1 - Q##0, Q##0); \
      const float c01 = fmaf((WZ), Q##3 - Q##2, Q##2); \
      const float c10 = fmaf((WZ), Q##5 - Q##4, Q##4); \
      const float c11 = fmaf((WZ), Q##7 - Q##6, Q##6); \
      const float c0  = fmaf((WY), c01 - c00, c00); \
      const float c1  = fmaf((WY), c11 - c10, c10); \
      (CV) = fmaf((WX), c1 - c0, c0); }

// Kernel 1: one block (256 threads) per ray; lane s = sample s.
// Run-leader dedup; ALL 40 gathers issued first, pinned live by an asm
// register barrier so the compiler cannot sink them -> single latency
// exposure, dense VMEM issue.
__global__ __launch_bounds__(256) void k_label(
        const float* __restrict__ x,
        const float* __restrict__ tlab,
        const float* __restrict__ wlab, const float* __restrict__ blab,
        float* __restrict__ hits, float* __restrict__ labels,
        int* __restrict__ firsts)
{
    const uint32_t P2 = 2654435761u, P3 = 805459861u;
    const int b = blockIdx.x;
    const int tid = threadIdx.x;
    const int lane = tid & 63;
    const int wid = tid >> 6;
    const float4 ray = *(const float4*)(x + 4 * (size_t)b);

    const int s_eff = tid < NS ? tid : NS - 1;
    const float t = (float)s_eff * (1.0f / 199.0f);
    const float px = ray.x * (1.0f - t) + ray.z * t;
    const float py = ray.y * (1.0f - t) + ray.w * t;
    const float pz = t;

    // finest level (res = 128); coarser levels derived by shifts
    const float xf4 = px * 128.0f, yf4 = py * 128.0f, zf4 = pz * 128.0f;
    const float fx4 = floorf(xf4), fy4 = floorf(yf4), fz4 = floorf(zf4);
    const uint32_t x4 = (uint32_t)(int)fx4;
    const uint32_t y4 = (uint32_t)(int)fy4;
    const uint32_t z4 = (uint32_t)(int)fz4;
    const uint32_t cell4 = x4 | (y4 << 10) | (z4 << 20);
    const uint32_t prev = __shfl_up(cell4, 1);
    const uint32_t diff = cell4 ^ prev;   // garbage at lane 0 (forced leader)

    // ---- leader masks / broadcast lanes for levels 0..3 ----
    int ldr0, ldr1, ldr2, ldr3;
    bool led0, led1, led2, led3;
    {
        #define LDRCALC(L, K, LED, LDR) { \
            const uint32_t fm = 0x3FFu & ~((1u << (K)) - 1u); \
            const uint32_t m_l = fm | (fm << 10) | (fm << 20); \
            LED = (lane == 0) || ((diff & m_l) != 0u); \
            const uint64_t bal = __ballot(LED); \
            const uint64_t below = bal & (~0ull >> (63 - lane)); \
            LDR = 63 - __clzll(below); }
        LDRCALC(0, 4, led0, ldr0)
        LDRCALC(1, 3, led1, ldr1)
        LDRCALC(2, 2, led2, ldr2)
        LDRCALC(3, 1, led3, ldr3)
        #undef LDRCALC
    }

    // ---- issue ALL loads (levels 0..3 leader-masked, level 4 full) ----
    DECL8(va) DECL8(vb) DECL8(vc) DECL8(vd) DECL8(ve)

    #define ISSUE(L, K, LED, P) { \
        if (LED) { \
            const uint32_t x0 = x4 >> (K), y0 = y4 >> (K), z0 = z4 >> (K); \
            const uint32_t hy0 = y0 * P2, hz0 = z0 * P3; \
            const uint32_t base = x0 ^ hy0 ^ hz0; \
            const uint32_t dx = x0 ^ (x0 + 1u); \
            const uint32_t dy = hy0 ^ (hy0 + P2); \
            const uint32_t dz = hz0 ^ (hz0 + P3); \
            const float* __restrict__ tl = tlab + (size_t)(L) * THASH; \
            LOAD8(P, tl, base, dx, dy, dz) } }
    ISSUE(0, 4, led0, va)
    ISSUE(1, 3, led1, vb)
    ISSUE(2, 2, led2, vc)
    ISSUE(3, 1, led3, vd)
    #undef ISSUE
    {
        const uint32_t hy0 = y4 * P2, hz0 = z4 * P3;
        const uint32_t base = x4 ^ hy0 ^ hz0;
        const uint32_t dx = x4 ^ (x4 + 1u);
        const uint32_t dy = hy0 ^ (hy0 + P2);
        const uint32_t dz = hz0 ^ (hz0 + P3);
        const float* __restrict__ tl = tlab + (size_t)4 * THASH;
        LOAD8(ve, tl, base, dx, dy, dz)
    }

    // ---- register barrier: pin all 40 loaded values live here ----
    asm volatile(""
        : "+v"(va0),"+v"(va1),"+v"(va2),"+v"(va3),"+v"(va4),"+v"(va5),"+v"(va6),"+v"(va7),
          "+v"(vb0),"+v"(vb1),"+v"(vb2),"+v"(vb3),"+v"(vb4),"+v"(vb5),"+v"(vb6),"+v"(vb7),
          "+v"(vc0),"+v"(vc1),"+v"(vc2),"+v"(vc3),"+v"(vc4),"+v"(vc5),"+v"(vc6),"+v"(vc7),
          "+v"(vd0),"+v"(vd1),"+v"(vd2),"+v"(vd3),"+v"(vd4),"+v"(vd5),"+v"(vd6),"+v"(vd7),
          "+v"(ve0),"+v"(ve1),"+v"(ve2),"+v"(ve3),"+v"(ve4),"+v"(ve5),"+v"(ve6),"+v"(ve7));

    // ---- consume: broadcast from leaders + trilinear interp ----
    float acc = blab[0];
    #define CONSUME(L, K, LDR, P) { \
        const uint32_t x0 = x4 >> (K), y0 = y4 >> (K), z0 = z4 >> (K); \
        const float sc = 1.0f / (float)(1 << (K)); \
        const float wx = fmaf(xf4, sc, -(float)x0); \
        const float wy = fmaf(yf4, sc, -(float)y0); \
        const float wz = fmaf(zf4, sc, -(float)z0); \
        float q0 = __shfl(P##0, LDR), q1 = __shfl(P##1, LDR); \
        float q2 = __shfl(P##2, LDR), q3 = __shfl(P##3, LDR); \
        float q4 = __shfl(P##4, LDR), q5 = __shfl(P##5, LDR); \
        float q6 = __shfl(P##6, LDR), q7 = __shfl(P##7, LDR); \
        float cv; \
        { const float c00 = fmaf(wz, q1 - q0, q0); \
          const float c01 = fmaf(wz, q3 - q2, q2); \
          const float c10 = fmaf(wz, q5 - q4, q4); \
          const float c11 = fmaf(wz, q7 - q6, q6); \
          const float c0  = fmaf(wy, c01 - c00, c00); \
          const float c1  = fmaf(wy, c11 - c10, c10); \
          cv = fmaf(wx, c1 - c0, c0); } \
        acc = fmaf(cv, wlab[L], acc); }
    CONSUME(0, 4, ldr0, va)
    CONSUME(1, 3, ldr1, vb)
    CONSUME(2, 2, ldr2, vc)
    CONSUME(3, 1, ldr3, vd)
    #undef CONSUME
    {
        const float wx = xf4 - fx4, wy = yf4 - fy4, wz = zf4 - fz4;
        float cv;
        LERP8(ve, wx, wy, wz, cv)
        acc = fmaf(cv, wlab[4], acc);
    }

    float lab = -1.0f;
    int cand = NS;
    if (tid < NS) {
        lab = sigmoidf_(acc);
        labels[(size_t)b * NS + tid] = lab;
        if (lab > 0.5f) cand = tid;
    }

    // ---- block reduce: max(label), min(first idx > 0.5) ----
    __shared__ float wmax[4];
    __shared__ int wmin[4];
    float m = lab;
    int c = cand;
    #pragma unroll
    for (int off = 32; off > 0; off >>= 1) {
        m = fmaxf(m, __shfl_xor(m, off));
        c = min(c, __shfl_xor(c, off));
    }
    if (lane == 0) { wmax[wid] = m; wmin[wid] = c; }
    __syncthreads();
    if (tid == 0) {
        float mm = fmaxf(fmaxf(wmax[0], wmax[1]), fmaxf(wmax[2], wmax[3]));
        int cc = min(min(wmin[0], wmin[1]), min(wmin[2], wmin[3]));
        hits[b] = mm;
        firsts[b] = (cc >= NS) ? 0 : cc;
    }
}

// Kernel 2: 512 blocks x 32 rays, 512 threads (8 waves).
// Phase A: 15 iters of one float4 gather/thread -> feat[32][120] in LDS.
// Phase B: each wave runs the MLP for 4 rays (W traffic halved vs RPB=16).
#define RPB 32
__global__ __launch_bounds__(512) void k_rgb(
        const float* __restrict__ x,
        const float* __restrict__ trgb,
        const int* __restrict__ firsts,
        const float* __restrict__ W1, const float* __restrict__ b1,
        const float* __restrict__ W2, const float* __restrict__ b2,
        const float* __restrict__ W3, const float* __restrict__ b3,
        const float* __restrict__ W4, const float* __restrict__ b4,
        float* __restrict__ rgb)
{
    const uint32_t P2 = 2654435761u, P3 = 805459861u;
    const int tid = threadIdx.x;
    const int lane = tid & 63;
    const int wid = tid >> 6;
    const int rayBase = blockIdx.x * RPB;

    __shared__ float feat[RPB][120];
    __shared__ float hs[RPB][64];

    // ---- Phase A: feature gather ----
    const int corner = tid & 7;
    const int rp = tid >> 3;          // 0..63
    const int ray = rp >> 1;          // 0..31
    const int pairHalf = rp & 1;
    const int bi = (corner >> 2) & 1, bj = (corner >> 1) & 1, bk = corner & 1;

    const float4 rd = *(const float4*)(x + 4 * (size_t)(rayBase + ray));
    const int first = firsts[rayBase + ray];

    #pragma unroll
    for (int it = 0; it < 15; ++it) {
        const int pair = pairHalf * 15 + it;   // 0..29
        const int si = pair / 6;
        const int l = pair % 6;
        int scl = first + si - 2;
        scl = scl < 0 ? 0 : (scl > NS - 1 ? NS - 1 : scl);
        const float t = (float)scl * (1.0f / 199.0f);
        const float px = rd.x * (1.0f - t) + rd.z * t;
        const float py = rd.y * (1.0f - t) + rd.w * t;
        const float pz = t;
        const int res = 4 << l;
        const float xf = px * (float)res, yf = py * (float)res, zf = pz * (float)res;
        const float fx = floorf(xf), fy = floorf(yf), fz = floorf(zf);
        const float wx = xf - fx, wy = yf - fy, wz = zf - fz;
        const uint32_t x0 = (uint32_t)(int)fx, y0 = (uint32_t)(int)fy, z0 = (uint32_t)(int)fz;
        const uint32_t hx = x0 + (uint32_t)bi;
        const uint32_t hy = (y0 + (uint32_t)bj) * P2;
        const uint32_t hz = (z0 + (uint32_t)bk) * P3;
        const uint32_t idx = (hx ^ hy ^ hz) & TMASK;
        const float cw = (bi ? wx : 1.0f - wx) * (bj ? wy : 1.0f - wy) * (bk ? wz : 1.0f - wz);
        const float4 tv = *(const float4*)(trgb + (((size_t)l << 19) + idx) * 4);
        float vx = tv.x * cw, vy = tv.y * cw, vz = tv.z * cw, vw = tv.w * cw;
        #pragma unroll
        for (int mm = 1; mm < 8; mm <<= 1) {
            vx += __shfl_xor(vx, mm);
            vy += __shfl_xor(vy, mm);
            vz += __shfl_xor(vz, mm);
            vw += __shfl_xor(vw, mm);
        }
        if (corner == 0) {
            float* f = &feat[ray][si * 24 + l * 4];
            f[0] = vx; f[1] = vy; f[2] = vz; f[3] = vw;
        }
    }
    __syncthreads();

    // ---- Phase B: MLP, 4 rays per wave ----
    const int r0 = wid * 4;

    float a0 = b1[lane], a1 = a0, a2 = a0, a3 = a0;
    #pragma unroll 6
    for (int i = 0; i < 120; i += 4) {
        const float4 f0 = *(const float4*)(&feat[r0 + 0][i]);
        const float4 f1 = *(const float4*)(&feat[r0 + 1][i]);
        const float4 f2 = *(const float4*)(&feat[r0 + 2][i]);
        const float4 f3 = *(const float4*)(&feat[r0 + 3][i]);
        #pragma unroll
        for (int j = 0; j < 4; ++j) {
            const float wv = W1[(i + j) * 64 + lane];
            a0 = fmaf(((const float*)&f0)[j], wv, a0);
            a1 = fmaf(((const float*)&f1)[j], wv, a1);
            a2 = fmaf(((const float*)&f2)[j], wv, a2);
            a3 = fmaf(((const float*)&f3)[j], wv, a3);
        }
    }
    hs[r0 + 0][lane] = fmaxf(a0, 0.f);
    hs[r0 + 1][lane] = fmaxf(a1, 0.f);
    hs[r0 + 2][lane] = fmaxf(a2, 0.f);
    hs[r0 + 3][lane] = fmaxf(a3, 0.f);
    __syncthreads();

    a0 = b2[lane]; a1 = a0; a2 = a0; a3 = a0;
    #pragma unroll 4
    for (int i = 0; i < 64; i += 4) {
        const float4 f0 = *(const float4*)(&hs[r0 + 0][i]);
        const float4 f1 = *(const float4*)(&hs[r0 + 1][i]);
        const float4 f2 = *(const float4*)(&hs[r0 + 2][i]);
        const float4 f3 = *(const float4*)(&hs[r0 + 3][i]);
        #pragma unroll
        for (int j = 0; j < 4; ++j) {
            const float wv = W2[(i + j) * 64 + lane];
            a0 = fmaf(((const float*)&f0)[j], wv, a0);
            a1 = fmaf(((const float*)&f1)[j], wv, a1);
            a2 = fmaf(((const float*)&f2)[j], wv, a2);
            a3 = fmaf(((const float*)&f3)[j], wv, a3);
        }
    }
    __syncthreads();
    hs[r0 + 0][lane] = fmaxf(a0, 0.f);
    hs[r0 + 1][lane] = fmaxf(a1, 0.f);
    hs[r0 + 2][lane] = fmaxf(a2, 0.f);
    hs[r0 + 3][lane] = fmaxf(a3, 0.f);
    __syncthreads();

    a0 = b3[lane]; a1 = a0; a2 = a0; a3 = a0;
    #pragma unroll 4
    for (int i = 0; i < 64; i += 4) {
        const float4 f0 = *(const float4*)(&hs[r0 + 0][i]);
        const float4 f1 = *(const float4*)(&hs[r0 + 1][i]);
        const float4 f2 = *(const float4*)(&hs[r0 + 2][i]);
        const float4 f3 = *(const float4*)(&hs[r0 + 3][i]);
        #pragma unroll
        for (int j = 0; j < 4; ++j) {
            const float wv = W3[(i + j) * 64 + lane];
            a0 = fmaf(((const float*)&f0)[j], wv, a0);
            a1 = fmaf(((const float*)&f1)[j], wv, a1);
            a2 = fmaf(((const float*)&f2)[j], wv, a2);
            a3 = fmaf(((const float*)&f3)[j], wv, a3);
        }
    }
    __syncthreads();
    hs[r0 + 0][lane] = fmaxf(a0, 0.f);
    hs[r0 + 1][lane] = fmaxf(a1, 0.f);
    hs[r0 + 2][lane] = fmaxf(a2, 0.f);
    hs[r0 + 3][lane] = fmaxf(a3, 0.f);
    __syncthreads();

    if (lane < 12) {
        const int r = lane / 3, ch = lane % 3;
        float acc = b4[ch];
        #pragma unroll 8
        for (int j = 0; j < 64; ++j)
            acc = fmaf(hs[r0 + r][j], W4[j * 3 + ch], acc);
        rgb[(size_t)(rayBase + r0 + r) * 3 + ch] = acc;
    }
}

extern "C" void kernel_launch(void* const* d_in, const int* in_sizes, int n_in,
                              void* d_out, int out_size, void* d_ws, size_t ws_size,
                              hipStream_t stream) {
    const float* x    = (const float*)d_in[0];
    const float* tlab = (const float*)d_in[1];
    const float* trgb = (const float*)d_in[2];
    const float* wlab = (const float*)d_in[3];
    const float* blab = (const float*)d_in[4];
    const float* W1   = (const float*)d_in[5];
    const float* b1   = (const float*)d_in[6];
    const float* W2   = (const float*)d_in[7];
    const float* b2   = (const float*)d_in[8];
    const float* W3   = (const float*)d_in[9];
    const float* b3   = (const float*)d_in[10];
    const float* W4   = (const float*)d_in[11];
    const float* b4   = (const float*)d_in[12];

    const int B = in_sizes[0] / 4;  // 16384

    float* hits   = (float*)d_out;                       // [B]
    float* labels = hits + B;                            // [B*NS]
    float* rgbout = labels + (size_t)B * NS;             // [B*3]
    int* firsts   = (int*)d_ws;                          // [B]

    k_label<<<B, 256, 0, stream>>>(x, tlab, wlab, blab, hits, labels, firsts);
    k_rgb<<<B / RPB, 512, 0, stream>>>(x, trgb, firsts,
                                       W1, b1, W2, b2, W3, b3, W4, b4, rgbout);
}